// Round 1
// baseline (511.273 us; speedup 1.0000x reference)
//
#include <hip/hip_runtime.h>
#include <math.h>

// B=8, C=64, H=W=256, WIN=8, NH=NW=32, P=64.
// FFT identity: ifft(fft(out1)+fft(out2)).real+imag == out1+out2.
// roll(-4)/roll(+4) fused into addressing: h=(wh*8+i+4)&255.
// All 7 matmuls -> mfma_f32_16x16x32_bf16 (fp32 accum). Softmax in-register on C-frags.
// Weights/qn read as fragments directly from global (L2-hot), LDS holds only bf16 tiles.
//
// R1: LDS buffer aliasing (VTs≡Xs, A1s≡Ts — disjoint lifetimes across existing barriers)
//     cuts LDS 55296->36864 B => 4 blocks/CU instead of 2 (__launch_bounds__(256,4)).
//     Kernel was latency-bound (MfmaUtil 4.9%, VALU 32%, HBM 10%, occupancy 22%).

typedef __attribute__((ext_vector_type(8))) short short8;
typedef __attribute__((ext_vector_type(4))) float f32x4;

#define LSTR 72  // bf16 row stride: 144B = 9 x 16B chunks -> odd chunk stride, banks spread

__device__ __forceinline__ short f2bf(float f) {  // RNE float->bf16
    unsigned u = __float_as_uint(f);
    u = u + 0x7FFFu + ((u >> 16) & 1u);
    return (short)(u >> 16);
}
__device__ __forceinline__ void unpack8(short8 h, float* f) {
#pragma unroll
    for (int j = 0; j < 8; ++j) f[j] = __uint_as_float(((unsigned)(unsigned short)h[j]) << 16);
}

__global__ void prep(const float* __restrict__ q, const float* __restrict__ kvw,
                     const float* __restrict__ pjw, short* __restrict__ qn_dp,
                     short* __restrict__ qn_pd, short* __restrict__ kvw_bf,
                     short* __restrict__ pjw_bf) {
    int bid = blockIdx.x, t = threadIdx.x;
    if (bid < 512) {                       // qn rows: b*64+d, l2norm over P=64
        float v = q[bid * 64 + t];
        float s = v * v;
#pragma unroll
        for (int off = 32; off > 0; off >>= 1) s += __shfl_xor(s, off, 64);
        float inv = 1.0f / fmaxf(sqrtf(s), 1e-12f);
        short h = f2bf(v * inv);
        int b = bid >> 6, d = bid & 63;
        qn_dp[b * 4096 + d * 64 + t] = h;  // [b][d][p]
        qn_pd[b * 4096 + t * 64 + d] = h;  // [b][p][d]
    } else {
        int idx = (bid - 512) * 64 + t;
        if (idx < 8192) kvw_bf[idx] = f2bf(kvw[idx]);
        else if (idx < 12288) pjw_bf[idx - 8192] = f2bf(pjw[idx - 8192]);
    }
}

__global__ void __launch_bounds__(256, 4)
attn_main(const float* __restrict__ xg, const short* __restrict__ qn_dp,
          const short* __restrict__ qn_pd, const short* __restrict__ kvw_bf,
          const float* __restrict__ dww, const short* __restrict__ pjw_bf,
          const float* __restrict__ rs1p, const float* __restrict__ rs2p,
          float* __restrict__ outg) {
    // 4 physical buffers; VTs aliases Xs, A1s aliases Ts (disjoint lifetimes):
    //   Xs:  x window [p][c-swz] -> (after half-1 conv1x1) VTs v^T [p][d-swz] -> O [p][ci-swz]
    //   Ts:  conv1x1 result [o][p] per half -> (after half-1 dwconv) attn probs A1/A2 [c][d]
    __shared__ short Xs[64 * LSTR];
    __shared__ short Ts[64 * LSTR];
    __shared__ short KNs[64 * LSTR];  // kn [c][p]
    __shared__ short Vs[64 * LSTR];   // v  [d][p]
#define VTs Xs
#define A1s Ts

    const int tid = threadIdx.x;
    const int w = tid >> 6, lane = tid & 63, lg = lane >> 4, ln = lane & 15;
    const int b = blockIdx.x & 7;            // batch -> XCD pinning
    const int widx = blockIdx.x >> 3;
    const int wh = widx >> 5, ww = widx & 31;
    const float rs1 = rs1p[0], rs2 = rs2p[0];

    // Prefetch qn fragments (B-operands for S1 / out2) from global (L2-hot).
    const short* qdp = qn_dp + b * 4096;
    const short* qpd = qn_pd + b * 4096;
    short8 fq1[8], fq2[8];
#pragma unroll
    for (int t = 0; t < 4; ++t)
#pragma unroll
        for (int kc = 0; kc < 2; ++kc) {
            fq1[t * 2 + kc] = *(const short8*)(qdp + (t * 16 + ln) * 64 + kc * 32 + lg * 8);
            fq2[t * 2 + kc] = *(const short8*)(qpd + (t * 16 + ln) * 64 + kc * 32 + lg * 8);
        }

    // ---- stage x window (rolled) into Xs[p][c-swz] bf16
#pragma unroll
    for (int rep = 0; rep < 2; ++rep) {
        int r = tid + rep * 256;
        int c = r >> 3, i = r & 7;
        int h = (wh * 8 + i + 4) & 255;
        const float* src = xg + (((b * 64 + c) * 256 + h) << 8);
        float4 av = *(const float4*)(src + ww * 8 + 4);
        float4 bv = *(const float4*)(src + ((ww * 8 + 8) & 255));
        float vals[8] = {av.x, av.y, av.z, av.w, bv.x, bv.y, bv.z, bv.w};
        int csw = ((((c >> 3) ^ i) & 7) << 3) | (c & 7);  // i == p>>3 for all 8 writes
#pragma unroll
        for (int j = 0; j < 8; ++j) Xs[(i * 8 + j) * LSTR + csw] = f2bf(vals[j]);
    }
    __syncthreads();

    // ================= conv1x1 + dwconv, K half then V half =================
#pragma unroll 1
    for (int half = 0; half < 2; ++half) {
        // conv1x1: T[o][p] = sum_c W[o][c] X[c][p]; A=W from global, B=X from LDS
        {
            f32x4 acc[4] = {};
            const short* Wg = kvw_bf + half * 4096;
#pragma unroll
            for (int kc = 0; kc < 2; ++kc) {
                short8 af = *(const short8*)(Wg + (w * 16 + ln) * 64 + kc * 32 + lg * 8);
#pragma unroll
                for (int t = 0; t < 4; ++t) {
                    int row = t * 16 + ln;
                    short8 bf = *(const short8*)&Xs[row * LSTR + ((((kc * 4 + lg) ^ (row >> 3)) & 7) << 3)];
                    acc[t] = __builtin_amdgcn_mfma_f32_16x16x32_bf16(af, bf, acc[t], 0, 0, 0);
                }
            }
#pragma unroll
            for (int t = 0; t < 4; ++t)
#pragma unroll
                for (int r = 0; r < 4; ++r)
                    Ts[(w * 16 + lg * 4 + r) * LSTR + t * 16 + ln] = f2bf(acc[t][r]);
        }
        __syncthreads();

        // dwconv 3x3 zero-padded in window; thread: channel o = tid>>2, rows 2q,2q+1
        {
            int o = tid >> 2, q = tid & 3;
            const float* wp = dww + (half * 64 + o) * 9;
            float wq[9];
#pragma unroll
            for (int k = 0; k < 9; ++k) wq[k] = wp[k];
            float rv[4][8];
#pragma unroll
            for (int dy = 0; dy < 4; ++dy) {
                int y = 2 * q - 1 + dy;
                if (y >= 0 && y < 8) {
                    short8 t8 = *(const short8*)&Ts[o * LSTR + y * 8];
                    unpack8(t8, rv[dy]);
                } else {
#pragma unroll
                    for (int j = 0; j < 8; ++j) rv[dy][j] = 0.f;
                }
            }
            float ov[16];
#pragma unroll
            for (int rr = 0; rr < 2; ++rr)
#pragma unroll
                for (int j = 0; j < 8; ++j) {
                    float a = 0.f;
#pragma unroll
                    for (int dy = 0; dy < 3; ++dy)
#pragma unroll
                        for (int dx = 0; dx < 3; ++dx) {
                            int xx = j + dx - 1;
                            if (xx >= 0 && xx < 8) a += wq[dy * 3 + dx] * rv[rr + dy][xx];
                        }
                    ov[rr * 8 + j] = a;
                }
            if (half == 0) {  // K: l2norm rows then kn -> KNs[c][p]
                float ss = 0.f;
#pragma unroll
                for (int k = 0; k < 16; ++k) ss += ov[k] * ov[k];
                ss += __shfl_xor(ss, 1);
                ss += __shfl_xor(ss, 2);
                float inv = 1.0f / fmaxf(sqrtf(ss), 1e-12f);
                short8 h0, h1;
#pragma unroll
                for (int k = 0; k < 8; ++k) { h0[k] = f2bf(ov[k] * inv); h1[k] = f2bf(ov[k + 8] * inv); }
                *(short8*)&KNs[o * LSTR + q * 16] = h0;
                *(short8*)&KNs[o * LSTR + q * 16 + 8] = h1;
            } else {          // V: Vs[d][p] + transposed VTs[p][d-swz] (VTs aliases Xs; all
                              // Xs reads finished at the barrier after half-1 conv1x1)
                short8 h0, h1;
#pragma unroll
                for (int k = 0; k < 8; ++k) { h0[k] = f2bf(ov[k]); h1[k] = f2bf(ov[k + 8]); }
                *(short8*)&Vs[o * LSTR + q * 16] = h0;
                *(short8*)&Vs[o * LSTR + q * 16 + 8] = h1;
#pragma unroll
                for (int k = 0; k < 16; ++k) {
                    int p = q * 16 + k;
                    int csw = ((((o >> 3) ^ (p >> 3)) & 7) << 3) | (o & 7);
                    VTs[p * LSTR + csw] = (k < 8) ? h0[k] : h1[k - 8];
                }
            }
        }
        __syncthreads();
    }

    const int arow = (w * 16 + ln) * LSTR;       // A-frag row base (m = w*16+ln)
    const int crow = w * 16 + lg * 4;            // C-frag row base

    // ================= S1 = kn . qn^T ; softmax in-register -> A1s =================
    // (A1s aliases Ts; all Ts reads finished at the barrier after half-1 dwconv)
    {
        f32x4 s1[4] = {};
#pragma unroll
        for (int kc = 0; kc < 2; ++kc) {
            short8 af = *(const short8*)&KNs[arow + kc * 32 + lg * 8];
#pragma unroll
            for (int t = 0; t < 4; ++t)
                s1[t] = __builtin_amdgcn_mfma_f32_16x16x32_bf16(af, fq1[t * 2 + kc], s1[t], 0, 0, 0);
        }
#pragma unroll
        for (int r = 0; r < 4; ++r) {
            float v0 = s1[0][r] * rs1, v1 = s1[1][r] * rs1, v2 = s1[2][r] * rs1, v3 = s1[3][r] * rs1;
            float m = fmaxf(fmaxf(v0, v1), fmaxf(v2, v3));
#pragma unroll
            for (int off = 1; off < 16; off <<= 1) m = fmaxf(m, __shfl_xor(m, off));
            float e0 = __expf(v0 - m), e1 = __expf(v1 - m), e2 = __expf(v2 - m), e3 = __expf(v3 - m);
            float s = e0 + e1 + e2 + e3;
#pragma unroll
            for (int off = 1; off < 16; off <<= 1) s += __shfl_xor(s, off);
            float inv = 1.0f / s;
            A1s[(crow + r) * LSTR + 0 * 16 + ln] = f2bf(e0 * inv);
            A1s[(crow + r) * LSTR + 1 * 16 + ln] = f2bf(e1 * inv);
            A1s[(crow + r) * LSTR + 2 * 16 + ln] = f2bf(e2 * inv);
            A1s[(crow + r) * LSTR + 3 * 16 + ln] = f2bf(e3 * inv);
        }
    }
    __syncthreads();

    // ================= out1 = A1 . V  ;  S2 = kn . V^T =================
    f32x4 o1[4] = {};
    f32x4 s2[4] = {};
    {
#pragma unroll
        for (int kc = 0; kc < 2; ++kc) {
            short8 af = *(const short8*)&A1s[arow + kc * 32 + lg * 8];
#pragma unroll
            for (int t = 0; t < 4; ++t) {
                int row = t * 16 + ln;
                short8 bf = *(const short8*)&VTs[row * LSTR + ((((kc * 4 + lg) ^ (row >> 3)) & 7) << 3)];
                o1[t] = __builtin_amdgcn_mfma_f32_16x16x32_bf16(af, bf, o1[t], 0, 0, 0);
            }
        }
#pragma unroll
        for (int kc = 0; kc < 2; ++kc) {
            short8 af = *(const short8*)&KNs[arow + kc * 32 + lg * 8];
#pragma unroll
            for (int t = 0; t < 4; ++t) {
                short8 bf = *(const short8*)&Vs[(t * 16 + ln) * LSTR + kc * 32 + lg * 8];
                s2[t] = __builtin_amdgcn_mfma_f32_16x16x32_bf16(af, bf, s2[t], 0, 0, 0);
            }
        }
    }
    __syncthreads();  // all A1/VTs reads done -> A1s reusable for A2, Xs reusable for O

    // softmax(S2) -> A2 (into A1s)
#pragma unroll
    for (int r = 0; r < 4; ++r) {
        float v0 = s2[0][r] * rs2, v1 = s2[1][r] * rs2, v2 = s2[2][r] * rs2, v3 = s2[3][r] * rs2;
        float m = fmaxf(fmaxf(v0, v1), fmaxf(v2, v3));
#pragma unroll
        for (int off = 1; off < 16; off <<= 1) m = fmaxf(m, __shfl_xor(m, off));
        float e0 = __expf(v0 - m), e1 = __expf(v1 - m), e2 = __expf(v2 - m), e3 = __expf(v3 - m);
        float s = e0 + e1 + e2 + e3;
#pragma unroll
        for (int off = 1; off < 16; off <<= 1) s += __shfl_xor(s, off);
        float inv = 1.0f / s;
        A1s[(crow + r) * LSTR + 0 * 16 + ln] = f2bf(e0 * inv);
        A1s[(crow + r) * LSTR + 1 * 16 + ln] = f2bf(e1 * inv);
        A1s[(crow + r) * LSTR + 2 * 16 + ln] = f2bf(e2 * inv);
        A1s[(crow + r) * LSTR + 3 * 16 + ln] = f2bf(e3 * inv);
    }
    __syncthreads();

    // ================= out2 = A2 . qn, accumulate into o1; O -> Xs[p][ci-swz] =================
    {
#pragma unroll
        for (int kc = 0; kc < 2; ++kc) {
            short8 af = *(const short8*)&A1s[arow + kc * 32 + lg * 8];
#pragma unroll
            for (int t = 0; t < 4; ++t)
                o1[t] = __builtin_amdgcn_mfma_f32_16x16x32_bf16(af, fq2[t * 2 + kc], o1[t], 0, 0, 0);
        }
#pragma unroll
        for (int t = 0; t < 4; ++t)
#pragma unroll
            for (int r = 0; r < 4; ++r) {
                int c = crow + r, p = t * 16 + ln;
                int csw = ((((c >> 3) ^ (p >> 3)) & 7) << 3) | (c & 7);
                Xs[p * LSTR + csw] = f2bf(o1[t][r]);
            }
    }
    __syncthreads();

    // ================= proj + scatter store (roll +4 fused) =================
    {
        f32x4 pr[4] = {};
#pragma unroll
        for (int kc = 0; kc < 2; ++kc) {
            short8 af = *(const short8*)(pjw_bf + (w * 16 + ln) * 64 + kc * 32 + lg * 8);
#pragma unroll
            for (int t = 0; t < 4; ++t) {
                int row = t * 16 + ln;
                short8 bf = *(const short8*)&Xs[row * LSTR + ((((kc * 4 + lg) ^ (row >> 3)) & 7) << 3)];
                pr[t] = __builtin_amdgcn_mfma_f32_16x16x32_bf16(af, bf, pr[t], 0, 0, 0);
            }
        }
#pragma unroll
        for (int t = 0; t < 4; ++t)
#pragma unroll
            for (int r = 0; r < 4; ++r) {
                int co = crow + r, p = t * 16 + ln;
                int h = (wh * 8 + (p >> 3) + 4) & 255;
                int wc = (ww * 8 + (p & 7) + 4) & 255;
                outg[((b * 64 + co) << 16) + (h << 8) + wc] = pr[t][r];
            }
    }
#undef VTs
#undef A1s
}

extern "C" void kernel_launch(void* const* d_in, const int* in_sizes, int n_in,
                              void* d_out, int out_size, void* d_ws, size_t ws_size,
                              hipStream_t stream) {
    const float* x = (const float*)d_in[0];
    const float* q = (const float*)d_in[1];
    const float* kvw = (const float*)d_in[2];
    const float* dww = (const float*)d_in[3];
    const float* pjw = (const float*)d_in[4];
    const float* rs1 = (const float*)d_in[5];
    const float* rs2 = (const float*)d_in[6];
    float* out = (float*)d_out;

    short* ws = (short*)d_ws;
    short* qn_dp = ws;                 // 8*4096 bf16
    short* qn_pd = ws + 32768;         // 8*4096 bf16
    short* kvw_bf = ws + 65536;        // 8192 bf16
    short* pjw_bf = ws + 73728;        // 4096 bf16

    prep<<<dim3(704), dim3(64), 0, stream>>>(q, kvw, pjw, qn_dp, qn_pd, kvw_bf, pjw_bf);
    attn_main<<<dim3(8192), dim3(256), 0, stream>>>(x, qn_dp, qn_pd, kvw_bf, dww, pjw_bf,
                                                    rs1, rs2, out);
}

// Round 2
// 409.043 us; speedup vs baseline: 1.2499x; 1.2499x over previous
//
#include <hip/hip_runtime.h>
#include <math.h>

// B=8, C=64, H=W=256, WIN=8, NH=NW=32, P=64.
// FFT identity: ifft(fft(out1)+fft(out2)).real+imag == out1+out2.
// roll(-4)/roll(+4) fused into addressing: h=(wh*8+i+4)&255.
// All 7 matmuls -> mfma_f32_16x16x32_bf16 (fp32 accum). Softmax in-register on C-frags.
// Weights/qn read as fragments directly from global (L2-hot), LDS holds only bf16 tiles.
//
// R1: LDS buffer aliasing (VTs≡Xs, A1s≡Ts) cuts LDS 55296->36864 B.
// R2: launch_bounds back to (256,2) — (256,4) forced VGPR 104->64 and spilled
//     (FETCH+WRITE went 0.20->1.1 GB; kernel became scratch-bound at 3.1 TB/s).
//     At VGPR=104 (128-granule) + 36864 B LDS, HW still fits 4 blocks/CU at runtime.

typedef __attribute__((ext_vector_type(8))) short short8;
typedef __attribute__((ext_vector_type(4))) float f32x4;

#define LSTR 72  // bf16 row stride: 144B = 9 x 16B chunks -> odd chunk stride, banks spread

__device__ __forceinline__ short f2bf(float f) {  // RNE float->bf16
    unsigned u = __float_as_uint(f);
    u = u + 0x7FFFu + ((u >> 16) & 1u);
    return (short)(u >> 16);
}
__device__ __forceinline__ void unpack8(short8 h, float* f) {
#pragma unroll
    for (int j = 0; j < 8; ++j) f[j] = __uint_as_float(((unsigned)(unsigned short)h[j]) << 16);
}

__global__ void prep(const float* __restrict__ q, const float* __restrict__ kvw,
                     const float* __restrict__ pjw, short* __restrict__ qn_dp,
                     short* __restrict__ qn_pd, short* __restrict__ kvw_bf,
                     short* __restrict__ pjw_bf) {
    int bid = blockIdx.x, t = threadIdx.x;
    if (bid < 512) {                       // qn rows: b*64+d, l2norm over P=64
        float v = q[bid * 64 + t];
        float s = v * v;
#pragma unroll
        for (int off = 32; off > 0; off >>= 1) s += __shfl_xor(s, off, 64);
        float inv = 1.0f / fmaxf(sqrtf(s), 1e-12f);
        short h = f2bf(v * inv);
        int b = bid >> 6, d = bid & 63;
        qn_dp[b * 4096 + d * 64 + t] = h;  // [b][d][p]
        qn_pd[b * 4096 + t * 64 + d] = h;  // [b][p][d]
    } else {
        int idx = (bid - 512) * 64 + t;
        if (idx < 8192) kvw_bf[idx] = f2bf(kvw[idx]);
        else if (idx < 12288) pjw_bf[idx - 8192] = f2bf(pjw[idx - 8192]);
    }
}

__global__ void __launch_bounds__(256, 2)
attn_main(const float* __restrict__ xg, const short* __restrict__ qn_dp,
          const short* __restrict__ qn_pd, const short* __restrict__ kvw_bf,
          const float* __restrict__ dww, const short* __restrict__ pjw_bf,
          const float* __restrict__ rs1p, const float* __restrict__ rs2p,
          float* __restrict__ outg) {
    // 4 physical buffers; VTs aliases Xs, A1s aliases Ts (disjoint lifetimes):
    //   Xs:  x window [p][c-swz] -> (after half-1 conv1x1) VTs v^T [p][d-swz] -> O [p][ci-swz]
    //   Ts:  conv1x1 result [o][p] per half -> (after half-1 dwconv) attn probs A1/A2 [c][d]
    __shared__ short Xs[64 * LSTR];
    __shared__ short Ts[64 * LSTR];
    __shared__ short KNs[64 * LSTR];  // kn [c][p]
    __shared__ short Vs[64 * LSTR];   // v  [d][p]
#define VTs Xs
#define A1s Ts

    const int tid = threadIdx.x;
    const int w = tid >> 6, lane = tid & 63, lg = lane >> 4, ln = lane & 15;
    const int b = blockIdx.x & 7;            // batch -> XCD pinning
    const int widx = blockIdx.x >> 3;
    const int wh = widx >> 5, ww = widx & 31;
    const float rs1 = rs1p[0], rs2 = rs2p[0];

    // Prefetch qn fragments (B-operands for S1 / out2) from global (L2-hot).
    const short* qdp = qn_dp + b * 4096;
    const short* qpd = qn_pd + b * 4096;
    short8 fq1[8], fq2[8];
#pragma unroll
    for (int t = 0; t < 4; ++t)
#pragma unroll
        for (int kc = 0; kc < 2; ++kc) {
            fq1[t * 2 + kc] = *(const short8*)(qdp + (t * 16 + ln) * 64 + kc * 32 + lg * 8);
            fq2[t * 2 + kc] = *(const short8*)(qpd + (t * 16 + ln) * 64 + kc * 32 + lg * 8);
        }

    // ---- stage x window (rolled) into Xs[p][c-swz] bf16
#pragma unroll
    for (int rep = 0; rep < 2; ++rep) {
        int r = tid + rep * 256;
        int c = r >> 3, i = r & 7;
        int h = (wh * 8 + i + 4) & 255;
        const float* src = xg + (((b * 64 + c) * 256 + h) << 8);
        float4 av = *(const float4*)(src + ww * 8 + 4);
        float4 bv = *(const float4*)(src + ((ww * 8 + 8) & 255));
        float vals[8] = {av.x, av.y, av.z, av.w, bv.x, bv.y, bv.z, bv.w};
        int csw = ((((c >> 3) ^ i) & 7) << 3) | (c & 7);  // i == p>>3 for all 8 writes
#pragma unroll
        for (int j = 0; j < 8; ++j) Xs[(i * 8 + j) * LSTR + csw] = f2bf(vals[j]);
    }
    __syncthreads();

    // ================= conv1x1 + dwconv, K half then V half =================
#pragma unroll 1
    for (int half = 0; half < 2; ++half) {
        // conv1x1: T[o][p] = sum_c W[o][c] X[c][p]; A=W from global, B=X from LDS
        {
            f32x4 acc[4] = {};
            const short* Wg = kvw_bf + half * 4096;
#pragma unroll
            for (int kc = 0; kc < 2; ++kc) {
                short8 af = *(const short8*)(Wg + (w * 16 + ln) * 64 + kc * 32 + lg * 8);
#pragma unroll
                for (int t = 0; t < 4; ++t) {
                    int row = t * 16 + ln;
                    short8 bf = *(const short8*)&Xs[row * LSTR + ((((kc * 4 + lg) ^ (row >> 3)) & 7) << 3)];
                    acc[t] = __builtin_amdgcn_mfma_f32_16x16x32_bf16(af, bf, acc[t], 0, 0, 0);
                }
            }
#pragma unroll
            for (int t = 0; t < 4; ++t)
#pragma unroll
                for (int r = 0; r < 4; ++r)
                    Ts[(w * 16 + lg * 4 + r) * LSTR + t * 16 + ln] = f2bf(acc[t][r]);
        }
        __syncthreads();

        // dwconv 3x3 zero-padded in window; thread: channel o = tid>>2, rows 2q,2q+1
        {
            int o = tid >> 2, q = tid & 3;
            const float* wp = dww + (half * 64 + o) * 9;
            float wq[9];
#pragma unroll
            for (int k = 0; k < 9; ++k) wq[k] = wp[k];
            float rv[4][8];
#pragma unroll
            for (int dy = 0; dy < 4; ++dy) {
                int y = 2 * q - 1 + dy;
                if (y >= 0 && y < 8) {
                    short8 t8 = *(const short8*)&Ts[o * LSTR + y * 8];
                    unpack8(t8, rv[dy]);
                } else {
#pragma unroll
                    for (int j = 0; j < 8; ++j) rv[dy][j] = 0.f;
                }
            }
            float ov[16];
#pragma unroll
            for (int rr = 0; rr < 2; ++rr)
#pragma unroll
                for (int j = 0; j < 8; ++j) {
                    float a = 0.f;
#pragma unroll
                    for (int dy = 0; dy < 3; ++dy)
#pragma unroll
                        for (int dx = 0; dx < 3; ++dx) {
                            int xx = j + dx - 1;
                            if (xx >= 0 && xx < 8) a += wq[dy * 3 + dx] * rv[rr + dy][xx];
                        }
                    ov[rr * 8 + j] = a;
                }
            if (half == 0) {  // K: l2norm rows then kn -> KNs[c][p]
                float ss = 0.f;
#pragma unroll
                for (int k = 0; k < 16; ++k) ss += ov[k] * ov[k];
                ss += __shfl_xor(ss, 1);
                ss += __shfl_xor(ss, 2);
                float inv = 1.0f / fmaxf(sqrtf(ss), 1e-12f);
                short8 h0, h1;
#pragma unroll
                for (int k = 0; k < 8; ++k) { h0[k] = f2bf(ov[k] * inv); h1[k] = f2bf(ov[k + 8] * inv); }
                *(short8*)&KNs[o * LSTR + q * 16] = h0;
                *(short8*)&KNs[o * LSTR + q * 16 + 8] = h1;
            } else {          // V: Vs[d][p] + transposed VTs[p][d-swz] (VTs aliases Xs; all
                              // Xs reads finished at the barrier after half-1 conv1x1)
                short8 h0, h1;
#pragma unroll
                for (int k = 0; k < 8; ++k) { h0[k] = f2bf(ov[k]); h1[k] = f2bf(ov[k + 8]); }
                *(short8*)&Vs[o * LSTR + q * 16] = h0;
                *(short8*)&Vs[o * LSTR + q * 16 + 8] = h1;
#pragma unroll
                for (int k = 0; k < 16; ++k) {
                    int p = q * 16 + k;
                    int csw = ((((o >> 3) ^ (p >> 3)) & 7) << 3) | (o & 7);
                    VTs[p * LSTR + csw] = (k < 8) ? h0[k] : h1[k - 8];
                }
            }
        }
        __syncthreads();
    }

    const int arow = (w * 16 + ln) * LSTR;       // A-frag row base (m = w*16+ln)
    const int crow = w * 16 + lg * 4;            // C-frag row base

    // ================= S1 = kn . qn^T ; softmax in-register -> A1s =================
    // (A1s aliases Ts; all Ts reads finished at the barrier after half-1 dwconv)
    {
        f32x4 s1[4] = {};
#pragma unroll
        for (int kc = 0; kc < 2; ++kc) {
            short8 af = *(const short8*)&KNs[arow + kc * 32 + lg * 8];
#pragma unroll
            for (int t = 0; t < 4; ++t)
                s1[t] = __builtin_amdgcn_mfma_f32_16x16x32_bf16(af, fq1[t * 2 + kc], s1[t], 0, 0, 0);
        }
#pragma unroll
        for (int r = 0; r < 4; ++r) {
            float v0 = s1[0][r] * rs1, v1 = s1[1][r] * rs1, v2 = s1[2][r] * rs1, v3 = s1[3][r] * rs1;
            float m = fmaxf(fmaxf(v0, v1), fmaxf(v2, v3));
#pragma unroll
            for (int off = 1; off < 16; off <<= 1) m = fmaxf(m, __shfl_xor(m, off));
            float e0 = __expf(v0 - m), e1 = __expf(v1 - m), e2 = __expf(v2 - m), e3 = __expf(v3 - m);
            float s = e0 + e1 + e2 + e3;
#pragma unroll
            for (int off = 1; off < 16; off <<= 1) s += __shfl_xor(s, off);
            float inv = 1.0f / s;
            A1s[(crow + r) * LSTR + 0 * 16 + ln] = f2bf(e0 * inv);
            A1s[(crow + r) * LSTR + 1 * 16 + ln] = f2bf(e1 * inv);
            A1s[(crow + r) * LSTR + 2 * 16 + ln] = f2bf(e2 * inv);
            A1s[(crow + r) * LSTR + 3 * 16 + ln] = f2bf(e3 * inv);
        }
    }
    __syncthreads();

    // ================= out1 = A1 . V  ;  S2 = kn . V^T =================
    f32x4 o1[4] = {};
    f32x4 s2[4] = {};
    {
#pragma unroll
        for (int kc = 0; kc < 2; ++kc) {
            short8 af = *(const short8*)&A1s[arow + kc * 32 + lg * 8];
#pragma unroll
            for (int t = 0; t < 4; ++t) {
                int row = t * 16 + ln;
                short8 bf = *(const short8*)&VTs[row * LSTR + ((((kc * 4 + lg) ^ (row >> 3)) & 7) << 3)];
                o1[t] = __builtin_amdgcn_mfma_f32_16x16x32_bf16(af, bf, o1[t], 0, 0, 0);
            }
        }
#pragma unroll
        for (int kc = 0; kc < 2; ++kc) {
            short8 af = *(const short8*)&KNs[arow + kc * 32 + lg * 8];
#pragma unroll
            for (int t = 0; t < 4; ++t) {
                short8 bf = *(const short8*)&Vs[(t * 16 + ln) * LSTR + kc * 32 + lg * 8];
                s2[t] = __builtin_amdgcn_mfma_f32_16x16x32_bf16(af, bf, s2[t], 0, 0, 0);
            }
        }
    }
    __syncthreads();  // all A1/VTs reads done -> A1s reusable for A2, Xs reusable for O

    // softmax(S2) -> A2 (into A1s)
#pragma unroll
    for (int r = 0; r < 4; ++r) {
        float v0 = s2[0][r] * rs2, v1 = s2[1][r] * rs2, v2 = s2[2][r] * rs2, v3 = s2[3][r] * rs2;
        float m = fmaxf(fmaxf(v0, v1), fmaxf(v2, v3));
#pragma unroll
        for (int off = 1; off < 16; off <<= 1) m = fmaxf(m, __shfl_xor(m, off));
        float e0 = __expf(v0 - m), e1 = __expf(v1 - m), e2 = __expf(v2 - m), e3 = __expf(v3 - m);
        float s = e0 + e1 + e2 + e3;
#pragma unroll
        for (int off = 1; off < 16; off <<= 1) s += __shfl_xor(s, off);
        float inv = 1.0f / s;
        A1s[(crow + r) * LSTR + 0 * 16 + ln] = f2bf(e0 * inv);
        A1s[(crow + r) * LSTR + 1 * 16 + ln] = f2bf(e1 * inv);
        A1s[(crow + r) * LSTR + 2 * 16 + ln] = f2bf(e2 * inv);
        A1s[(crow + r) * LSTR + 3 * 16 + ln] = f2bf(e3 * inv);
    }
    __syncthreads();

    // ================= out2 = A2 . qn, accumulate into o1; O -> Xs[p][ci-swz] =================
    {
#pragma unroll
        for (int kc = 0; kc < 2; ++kc) {
            short8 af = *(const short8*)&A1s[arow + kc * 32 + lg * 8];
#pragma unroll
            for (int t = 0; t < 4; ++t)
                o1[t] = __builtin_amdgcn_mfma_f32_16x16x32_bf16(af, fq2[t * 2 + kc], o1[t], 0, 0, 0);
        }
#pragma unroll
        for (int t = 0; t < 4; ++t)
#pragma unroll
            for (int r = 0; r < 4; ++r) {
                int c = crow + r, p = t * 16 + ln;
                int csw = ((((c >> 3) ^ (p >> 3)) & 7) << 3) | (c & 7);
                Xs[p * LSTR + csw] = f2bf(o1[t][r]);
            }
    }
    __syncthreads();

    // ================= proj + scatter store (roll +4 fused) =================
    {
        f32x4 pr[4] = {};
#pragma unroll
        for (int kc = 0; kc < 2; ++kc) {
            short8 af = *(const short8*)(pjw_bf + (w * 16 + ln) * 64 + kc * 32 + lg * 8);
#pragma unroll
            for (int t = 0; t < 4; ++t) {
                int row = t * 16 + ln;
                short8 bf = *(const short8*)&Xs[row * LSTR + ((((kc * 4 + lg) ^ (row >> 3)) & 7) << 3)];
                pr[t] = __builtin_amdgcn_mfma_f32_16x16x32_bf16(af, bf, pr[t], 0, 0, 0);
            }
        }
#pragma unroll
        for (int t = 0; t < 4; ++t)
#pragma unroll
            for (int r = 0; r < 4; ++r) {
                int co = crow + r, p = t * 16 + ln;
                int h = (wh * 8 + (p >> 3) + 4) & 255;
                int wc = (ww * 8 + (p & 7) + 4) & 255;
                outg[((b * 64 + co) << 16) + (h << 8) + wc] = pr[t][r];
            }
    }
#undef VTs
#undef A1s
}

extern "C" void kernel_launch(void* const* d_in, const int* in_sizes, int n_in,
                              void* d_out, int out_size, void* d_ws, size_t ws_size,
                              hipStream_t stream) {
    const float* x = (const float*)d_in[0];
    const float* q = (const float*)d_in[1];
    const float* kvw = (const float*)d_in[2];
    const float* dww = (const float*)d_in[3];
    const float* pjw = (const float*)d_in[4];
    const float* rs1 = (const float*)d_in[5];
    const float* rs2 = (const float*)d_in[6];
    float* out = (float*)d_out;

    short* ws = (short*)d_ws;
    short* qn_dp = ws;                 // 8*4096 bf16
    short* qn_pd = ws + 32768;         // 8*4096 bf16
    short* kvw_bf = ws + 65536;        // 8192 bf16
    short* pjw_bf = ws + 73728;        // 4096 bf16

    prep<<<dim3(704), dim3(64), 0, stream>>>(q, kvw, pjw, qn_dp, qn_pd, kvw_bf, pjw_bf);
    attn_main<<<dim3(8192), dim3(256), 0, stream>>>(x, qn_dp, qn_pd, kvw_bf, dww, pjw_bf,
                                                    rs1, rs2, out);
}

// Round 3
// 363.984 us; speedup vs baseline: 1.4047x; 1.1238x over previous
//
#include <hip/hip_runtime.h>
#include <math.h>

// B=8, C=64, H=W=256, WIN=8, NH=NW=32, P=64.
// FFT identity: ifft(fft(out1)+fft(out2)).real+imag == out1+out2.
// roll(-4)/roll(+4) fused into addressing: h=(wh*8+i+4)&255.
// All 7 matmuls -> mfma_f32_16x16x32_bf16 (fp32 accum). Softmax in-register on C-frags.
// Weights/qn read as fragments directly from global (L2-hot), LDS holds only bf16 tiles.
//
// R1: LDS buffer aliasing (VTs≡Xs, A1s≡Ts) cuts LDS 55296->36864 B.
// R2: (256,4) forced total-regs<=128 -> arch VGPR 64 + scratch spill (1.1 GB HBM). Reverted.
// R3: occupancy is capped by TOTAL (arch+AGPR) regs/wave, not LDS. Kill the 64-VGPR
//     whole-kernel fq1/fq2 prefetch: load qn fragments at point of use (L2-hot, barriers
//     are scheduling boundaries so loads stay in their sections). Target total <=170
//     (3 waves/EU) or <=128 (4) without forced spill; keep (256,2) as a floor only.

typedef __attribute__((ext_vector_type(8))) short short8;
typedef __attribute__((ext_vector_type(4))) float f32x4;

#define LSTR 72  // bf16 row stride: 144B = 9 x 16B chunks -> odd chunk stride, banks spread

__device__ __forceinline__ short f2bf(float f) {  // RNE float->bf16
    unsigned u = __float_as_uint(f);
    u = u + 0x7FFFu + ((u >> 16) & 1u);
    return (short)(u >> 16);
}
__device__ __forceinline__ void unpack8(short8 h, float* f) {
#pragma unroll
    for (int j = 0; j < 8; ++j) f[j] = __uint_as_float(((unsigned)(unsigned short)h[j]) << 16);
}

__global__ void prep(const float* __restrict__ q, const float* __restrict__ kvw,
                     const float* __restrict__ pjw, short* __restrict__ qn_dp,
                     short* __restrict__ qn_pd, short* __restrict__ kvw_bf,
                     short* __restrict__ pjw_bf) {
    int bid = blockIdx.x, t = threadIdx.x;
    if (bid < 512) {                       // qn rows: b*64+d, l2norm over P=64
        float v = q[bid * 64 + t];
        float s = v * v;
#pragma unroll
        for (int off = 32; off > 0; off >>= 1) s += __shfl_xor(s, off, 64);
        float inv = 1.0f / fmaxf(sqrtf(s), 1e-12f);
        short h = f2bf(v * inv);
        int b = bid >> 6, d = bid & 63;
        qn_dp[b * 4096 + d * 64 + t] = h;  // [b][d][p]
        qn_pd[b * 4096 + t * 64 + d] = h;  // [b][p][d]
    } else {
        int idx = (bid - 512) * 64 + t;
        if (idx < 8192) kvw_bf[idx] = f2bf(kvw[idx]);
        else if (idx < 12288) pjw_bf[idx - 8192] = f2bf(pjw[idx - 8192]);
    }
}

__global__ void __launch_bounds__(256, 2)
attn_main(const float* __restrict__ xg, const short* __restrict__ qn_dp,
          const short* __restrict__ qn_pd, const short* __restrict__ kvw_bf,
          const float* __restrict__ dww, const short* __restrict__ pjw_bf,
          const float* __restrict__ rs1p, const float* __restrict__ rs2p,
          float* __restrict__ outg) {
    // 4 physical buffers; VTs aliases Xs, A1s aliases Ts (disjoint lifetimes):
    //   Xs:  x window [p][c-swz] -> (after half-1 conv1x1) VTs v^T [p][d-swz] -> O [p][ci-swz]
    //   Ts:  conv1x1 result [o][p] per half -> (after half-1 dwconv) attn probs A1/A2 [c][d]
    __shared__ short Xs[64 * LSTR];
    __shared__ short Ts[64 * LSTR];
    __shared__ short KNs[64 * LSTR];  // kn [c][p]
    __shared__ short Vs[64 * LSTR];   // v  [d][p]
#define VTs Xs
#define A1s Ts

    const int tid = threadIdx.x;
    const int w = tid >> 6, lane = tid & 63, lg = lane >> 4, ln = lane & 15;
    const int b = blockIdx.x & 7;            // batch -> XCD pinning
    const int widx = blockIdx.x >> 3;
    const int wh = widx >> 5, ww = widx & 31;
    const float rs1 = rs1p[0], rs2 = rs2p[0];

    const short* qdp = qn_dp + b * 4096;  // qn [d][p] (L2-hot, loaded at use)
    const short* qpd = qn_pd + b * 4096;  // qn [p][d]

    // ---- stage x window (rolled) into Xs[p][c-swz] bf16
#pragma unroll
    for (int rep = 0; rep < 2; ++rep) {
        int r = tid + rep * 256;
        int c = r >> 3, i = r & 7;
        int h = (wh * 8 + i + 4) & 255;
        const float* src = xg + (((b * 64 + c) * 256 + h) << 8);
        float4 av = *(const float4*)(src + ww * 8 + 4);
        float4 bv = *(const float4*)(src + ((ww * 8 + 8) & 255));
        float vals[8] = {av.x, av.y, av.z, av.w, bv.x, bv.y, bv.z, bv.w};
        int csw = ((((c >> 3) ^ i) & 7) << 3) | (c & 7);  // i == p>>3 for all 8 writes
#pragma unroll
        for (int j = 0; j < 8; ++j) Xs[(i * 8 + j) * LSTR + csw] = f2bf(vals[j]);
    }
    __syncthreads();

    // ================= conv1x1 + dwconv, K half then V half =================
#pragma unroll 1
    for (int half = 0; half < 2; ++half) {
        // conv1x1: T[o][p] = sum_c W[o][c] X[c][p]; A=W from global, B=X from LDS
        {
            f32x4 acc[4] = {};
            const short* Wg = kvw_bf + half * 4096;
#pragma unroll
            for (int kc = 0; kc < 2; ++kc) {
                short8 af = *(const short8*)(Wg + (w * 16 + ln) * 64 + kc * 32 + lg * 8);
#pragma unroll
                for (int t = 0; t < 4; ++t) {
                    int row = t * 16 + ln;
                    short8 bf = *(const short8*)&Xs[row * LSTR + ((((kc * 4 + lg) ^ (row >> 3)) & 7) << 3)];
                    acc[t] = __builtin_amdgcn_mfma_f32_16x16x32_bf16(af, bf, acc[t], 0, 0, 0);
                }
            }
#pragma unroll
            for (int t = 0; t < 4; ++t)
#pragma unroll
                for (int r = 0; r < 4; ++r)
                    Ts[(w * 16 + lg * 4 + r) * LSTR + t * 16 + ln] = f2bf(acc[t][r]);
        }
        __syncthreads();

        // dwconv 3x3 zero-padded in window; thread: channel o = tid>>2, rows 2q,2q+1
        {
            int o = tid >> 2, q = tid & 3;
            const float* wp = dww + (half * 64 + o) * 9;
            float wq[9];
#pragma unroll
            for (int k = 0; k < 9; ++k) wq[k] = wp[k];
            float rv[4][8];
#pragma unroll
            for (int dy = 0; dy < 4; ++dy) {
                int y = 2 * q - 1 + dy;
                if (y >= 0 && y < 8) {
                    short8 t8 = *(const short8*)&Ts[o * LSTR + y * 8];
                    unpack8(t8, rv[dy]);
                } else {
#pragma unroll
                    for (int j = 0; j < 8; ++j) rv[dy][j] = 0.f;
                }
            }
            float ov[16];
#pragma unroll
            for (int rr = 0; rr < 2; ++rr)
#pragma unroll
                for (int j = 0; j < 8; ++j) {
                    float a = 0.f;
#pragma unroll
                    for (int dy = 0; dy < 3; ++dy)
#pragma unroll
                        for (int dx = 0; dx < 3; ++dx) {
                            int xx = j + dx - 1;
                            if (xx >= 0 && xx < 8) a += wq[dy * 3 + dx] * rv[rr + dy][xx];
                        }
                    ov[rr * 8 + j] = a;
                }
            if (half == 0) {  // K: l2norm rows then kn -> KNs[c][p]
                float ss = 0.f;
#pragma unroll
                for (int k = 0; k < 16; ++k) ss += ov[k] * ov[k];
                ss += __shfl_xor(ss, 1);
                ss += __shfl_xor(ss, 2);
                float inv = 1.0f / fmaxf(sqrtf(ss), 1e-12f);
                short8 h0, h1;
#pragma unroll
                for (int k = 0; k < 8; ++k) { h0[k] = f2bf(ov[k] * inv); h1[k] = f2bf(ov[k + 8] * inv); }
                *(short8*)&KNs[o * LSTR + q * 16] = h0;
                *(short8*)&KNs[o * LSTR + q * 16 + 8] = h1;
            } else {          // V: Vs[d][p] + transposed VTs[p][d-swz] (VTs aliases Xs; all
                              // Xs reads finished at the barrier after half-1 conv1x1)
                short8 h0, h1;
#pragma unroll
                for (int k = 0; k < 8; ++k) { h0[k] = f2bf(ov[k]); h1[k] = f2bf(ov[k + 8]); }
                *(short8*)&Vs[o * LSTR + q * 16] = h0;
                *(short8*)&Vs[o * LSTR + q * 16 + 8] = h1;
#pragma unroll
                for (int k = 0; k < 16; ++k) {
                    int p = q * 16 + k;
                    int csw = ((((o >> 3) ^ (p >> 3)) & 7) << 3) | (o & 7);
                    VTs[p * LSTR + csw] = (k < 8) ? h0[k] : h1[k - 8];
                }
            }
        }
        __syncthreads();
    }

    const int arow = (w * 16 + ln) * LSTR;       // A-frag row base (m = w*16+ln)
    const int crow = w * 16 + lg * 4;            // C-frag row base

    // ================= S1 = kn . qn^T ; softmax in-register -> A1s =================
    // (A1s aliases Ts; all Ts reads finished at the barrier after half-1 dwconv)
    // qn B-frags loaded here from global (L2-hot) — not held across the kernel.
    {
        f32x4 s1[4] = {};
#pragma unroll
        for (int kc = 0; kc < 2; ++kc) {
            short8 af = *(const short8*)&KNs[arow + kc * 32 + lg * 8];
#pragma unroll
            for (int t = 0; t < 4; ++t) {
                short8 fb = *(const short8*)(qdp + (t * 16 + ln) * 64 + kc * 32 + lg * 8);
                s1[t] = __builtin_amdgcn_mfma_f32_16x16x32_bf16(af, fb, s1[t], 0, 0, 0);
            }
        }
#pragma unroll
        for (int r = 0; r < 4; ++r) {
            float v0 = s1[0][r] * rs1, v1 = s1[1][r] * rs1, v2 = s1[2][r] * rs1, v3 = s1[3][r] * rs1;
            float m = fmaxf(fmaxf(v0, v1), fmaxf(v2, v3));
#pragma unroll
            for (int off = 1; off < 16; off <<= 1) m = fmaxf(m, __shfl_xor(m, off));
            float e0 = __expf(v0 - m), e1 = __expf(v1 - m), e2 = __expf(v2 - m), e3 = __expf(v3 - m);
            float s = e0 + e1 + e2 + e3;
#pragma unroll
            for (int off = 1; off < 16; off <<= 1) s += __shfl_xor(s, off);
            float inv = 1.0f / s;
            A1s[(crow + r) * LSTR + 0 * 16 + ln] = f2bf(e0 * inv);
            A1s[(crow + r) * LSTR + 1 * 16 + ln] = f2bf(e1 * inv);
            A1s[(crow + r) * LSTR + 2 * 16 + ln] = f2bf(e2 * inv);
            A1s[(crow + r) * LSTR + 3 * 16 + ln] = f2bf(e3 * inv);
        }
    }
    __syncthreads();

    // ================= out1 = A1 . V  ;  S2 = kn . V^T =================
    f32x4 o1[4] = {};
    f32x4 s2[4] = {};
    {
#pragma unroll
        for (int kc = 0; kc < 2; ++kc) {
            short8 af = *(const short8*)&A1s[arow + kc * 32 + lg * 8];
#pragma unroll
            for (int t = 0; t < 4; ++t) {
                int row = t * 16 + ln;
                short8 bf = *(const short8*)&VTs[row * LSTR + ((((kc * 4 + lg) ^ (row >> 3)) & 7) << 3)];
                o1[t] = __builtin_amdgcn_mfma_f32_16x16x32_bf16(af, bf, o1[t], 0, 0, 0);
            }
        }
#pragma unroll
        for (int kc = 0; kc < 2; ++kc) {
            short8 af = *(const short8*)&KNs[arow + kc * 32 + lg * 8];
#pragma unroll
            for (int t = 0; t < 4; ++t) {
                short8 bf = *(const short8*)&Vs[(t * 16 + ln) * LSTR + kc * 32 + lg * 8];
                s2[t] = __builtin_amdgcn_mfma_f32_16x16x32_bf16(af, bf, s2[t], 0, 0, 0);
            }
        }
    }
    __syncthreads();  // all A1/VTs reads done -> A1s reusable for A2, Xs reusable for O

    // softmax(S2) -> A2 (into A1s)
#pragma unroll
    for (int r = 0; r < 4; ++r) {
        float v0 = s2[0][r] * rs2, v1 = s2[1][r] * rs2, v2 = s2[2][r] * rs2, v3 = s2[3][r] * rs2;
        float m = fmaxf(fmaxf(v0, v1), fmaxf(v2, v3));
#pragma unroll
        for (int off = 1; off < 16; off <<= 1) m = fmaxf(m, __shfl_xor(m, off));
        float e0 = __expf(v0 - m), e1 = __expf(v1 - m), e2 = __expf(v2 - m), e3 = __expf(v3 - m);
        float s = e0 + e1 + e2 + e3;
#pragma unroll
        for (int off = 1; off < 16; off <<= 1) s += __shfl_xor(s, off);
        float inv = 1.0f / s;
        A1s[(crow + r) * LSTR + 0 * 16 + ln] = f2bf(e0 * inv);
        A1s[(crow + r) * LSTR + 1 * 16 + ln] = f2bf(e1 * inv);
        A1s[(crow + r) * LSTR + 2 * 16 + ln] = f2bf(e2 * inv);
        A1s[(crow + r) * LSTR + 3 * 16 + ln] = f2bf(e3 * inv);
    }
    __syncthreads();

    // ================= out2 = A2 . qn, accumulate into o1; O -> Xs[p][ci-swz] =================
    // qn^T B-frags loaded here from global (L2-hot).
    {
#pragma unroll
        for (int kc = 0; kc < 2; ++kc) {
            short8 af = *(const short8*)&A1s[arow + kc * 32 + lg * 8];
#pragma unroll
            for (int t = 0; t < 4; ++t) {
                short8 fb = *(const short8*)(qpd + (t * 16 + ln) * 64 + kc * 32 + lg * 8);
                o1[t] = __builtin_amdgcn_mfma_f32_16x16x32_bf16(af, fb, o1[t], 0, 0, 0);
            }
        }
#pragma unroll
        for (int t = 0; t < 4; ++t)
#pragma unroll
            for (int r = 0; r < 4; ++r) {
                int c = crow + r, p = t * 16 + ln;
                int csw = ((((c >> 3) ^ (p >> 3)) & 7) << 3) | (c & 7);
                Xs[p * LSTR + csw] = f2bf(o1[t][r]);
            }
    }
    __syncthreads();

    // ================= proj + scatter store (roll +4 fused) =================
    {
        f32x4 pr[4] = {};
#pragma unroll
        for (int kc = 0; kc < 2; ++kc) {
            short8 af = *(const short8*)(pjw_bf + (w * 16 + ln) * 64 + kc * 32 + lg * 8);
#pragma unroll
            for (int t = 0; t < 4; ++t) {
                int row = t * 16 + ln;
                short8 bf = *(const short8*)&Xs[row * LSTR + ((((kc * 4 + lg) ^ (row >> 3)) & 7) << 3)];
                pr[t] = __builtin_amdgcn_mfma_f32_16x16x32_bf16(af, bf, pr[t], 0, 0, 0);
            }
        }
#pragma unroll
        for (int t = 0; t < 4; ++t)
#pragma unroll
            for (int r = 0; r < 4; ++r) {
                int co = crow + r, p = t * 16 + ln;
                int h = (wh * 8 + (p >> 3) + 4) & 255;
                int wc = (ww * 8 + (p & 7) + 4) & 255;
                outg[((b * 64 + co) << 16) + (h << 8) + wc] = pr[t][r];
            }
    }
#undef VTs
#undef A1s
}

extern "C" void kernel_launch(void* const* d_in, const int* in_sizes, int n_in,
                              void* d_out, int out_size, void* d_ws, size_t ws_size,
                              hipStream_t stream) {
    const float* x = (const float*)d_in[0];
    const float* q = (const float*)d_in[1];
    const float* kvw = (const float*)d_in[2];
    const float* dww = (const float*)d_in[3];
    const float* pjw = (const float*)d_in[4];
    const float* rs1 = (const float*)d_in[5];
    const float* rs2 = (const float*)d_in[6];
    float* out = (float*)d_out;

    short* ws = (short*)d_ws;
    short* qn_dp = ws;                 // 8*4096 bf16
    short* qn_pd = ws + 32768;         // 8*4096 bf16
    short* kvw_bf = ws + 65536;        // 8192 bf16
    short* pjw_bf = ws + 73728;        // 4096 bf16

    prep<<<dim3(704), dim3(64), 0, stream>>>(q, kvw, pjw, qn_dp, qn_pd, kvw_bf, pjw_bf);
    attn_main<<<dim3(8192), dim3(256), 0, stream>>>(x, qn_dp, qn_pd, kvw_bf, dww, pjw_bf,
                                                    rs1, rs2, out);
}